// Round 3
// baseline (672.706 us; speedup 1.0000x reference)
//
#include <hip/hip_runtime.h>
#include <math.h>

#define NSAMP 32768
#define FS_F 44100.0f
#define PI_F 3.14159265358979323846f
#define NK 12  // ceil(735/64): max KS slots per sub-chunk

struct BParams {
  float alpha, alpha_p;
  float fr, g, s;
  int Di;
  float lc, lm, lp;
};

__device__ inline float sigmoidf_(float x) { return 1.0f / (1.0f + expf(-x)); }

__device__ inline BParams compute_params(int b, const float* __restrict__ pitch,
                                         const float* __restrict__ w1,
                                         const float* __restrict__ b1,
                                         const float* __restrict__ w2,
                                         const float* __restrict__ b2) {
  BParams P;
  float p = pitch[b];
  float h[16];
#pragma unroll
  for (int i = 0; i < 16; ++i) {
    float v = fmaf(p, w1[i], b1[i]);
    h[i] = v > 0.0f ? v : 0.0f;
  }
  float m[3];
#pragma unroll
  for (int j = 0; j < 3; ++j) {
    float acc = b2[j];
#pragma unroll
    for (int i = 0; i < 16; ++i) acc = fmaf(h[i], w2[j * 16 + i], acc);
    m[j] = acc;
  }
  P.lc = fminf(fmaxf(m[0], -2.0f), 2.5f);
  P.lm = fminf(fmaxf(m[1], -2.5f), 0.0f);
  P.lp = fminf(fmaxf(m[2], -4.0f), 4.0f);
  P.g = 0.999f * sigmoidf_(P.lc);
  P.s = sigmoidf_(P.lm);
  float f0 = fmaxf(p, 60.0f);
  float D = fminf(fmaxf(FS_F / f0, 2.0f), 735.0f);
  int Di = (int)floorf(D);
  P.fr = D - (float)Di;
  P.Di = Di;
  float mult = fminf(fmaxf(2.0f + 6.0f * (f0 - 60.0f) / 600.0f, 2.0f), 8.0f);
  float cutoff = fminf(2.0f * PI_F * f0 * mult / FS_F, PI_F * 0.9f);
  P.alpha = 1.0f - expf(-cutoff);
  float cpost = fminf(PI_F * sigmoidf_(P.lp), PI_F * 0.99f);
  P.alpha_p = 1.0f - expf(-cpost);
  return P;
}

// lane helpers (wave64)
__device__ inline float rl63(float v) {
  return __int_as_float(__builtin_amdgcn_readlane(__float_as_int(v), 63));
}
__device__ inline float rlv(float v, int l) {
  return __int_as_float(__builtin_amdgcn_readlane(__float_as_int(v), l));
}
// whole-wave shift right by 1; lane 0 takes `bnd` (uniform value)
__device__ inline float shr1(float v, float bnd) {
  return __int_as_float(__builtin_amdgcn_update_dpp(
      __float_as_int(bnd), __float_as_int(v), 0x138 /*wave_shr:1*/, 0xf, 0xf,
      false));
}

// Exact one-pole IIR y[n] = scale*x[n] + c*y[n-1] over NSAMP, 256 threads.
// Per-thread 8-float segments (dense float4 loads), Kogge-Stone shuffle scan
// with uniform ratio c^8 (segment transfer matrix is the scalar c^8), serial
// cross-wave carry over 4 wave aggregates. lws: 8 floats LDS.
__device__ inline void lpc_scan2(const float* __restrict__ in,
                                 float* __restrict__ out, float scale, float c,
                                 int t, float* lws) {
  const int lane = t & 63, wid = t >> 6;
  float c2v = c * c, c4 = c2v * c2v, c8 = c4 * c4;
  float m1 = c8, m2 = m1 * m1, m4 = m2 * m2, m8 = m4 * m4, m16 = m8 * m8,
        m32 = m16 * m16;
  float c512 = m32 * m32;
  float c2048 = c512 * c512;
  c2048 *= c2048;
  float l2c = log2f(c);  // c in (0,1), >= ~0.04
  float c8lane = exp2f((float)(8 * lane) * l2c);  // c^(8*lane), underflow->0 ok
  float cgk = exp2f((float)(8 * t) * l2c);        // c^(8*t)
  float vrun = 0.0f;
  const float4* in4 = (const float4*)in;
  float4* out4 = (float4*)out;
  for (int tile = 0; tile < 16; ++tile) {
    __syncthreads();  // lws reuse guard
    float4 xa = in4[(tile << 9) + 2 * t];
    float4 xb = in4[(tile << 9) + 2 * t + 1];
    float S = 0.0f;
    S = fmaf(c, S, scale * xa.x);
    S = fmaf(c, S, scale * xa.y);
    S = fmaf(c, S, scale * xa.z);
    S = fmaf(c, S, scale * xa.w);
    S = fmaf(c, S, scale * xb.x);
    S = fmaf(c, S, scale * xb.y);
    S = fmaf(c, S, scale * xb.z);
    S = fmaf(c, S, scale * xb.w);
    float Sw = S, u;
    u = __shfl_up(Sw, 1);
    if (lane >= 1) Sw = fmaf(m1, u, Sw);
    u = __shfl_up(Sw, 2);
    if (lane >= 2) Sw = fmaf(m2, u, Sw);
    u = __shfl_up(Sw, 4);
    if (lane >= 4) Sw = fmaf(m4, u, Sw);
    u = __shfl_up(Sw, 8);
    if (lane >= 8) Sw = fmaf(m8, u, Sw);
    u = __shfl_up(Sw, 16);
    if (lane >= 16) Sw = fmaf(m16, u, Sw);
    u = __shfl_up(Sw, 32);
    if (lane >= 32) Sw = fmaf(m32, u, Sw);
    if (lane == 63) lws[wid] = Sw;
    __syncthreads();
    float a0 = lws[0], a1w = lws[1], a2w = lws[2], a3w = lws[3];
    float carry = (wid == 1)   ? a0
                  : (wid == 2) ? fmaf(c512, a0, a1w)
                  : (wid == 3) ? fmaf(c512, fmaf(c512, a0, a1w), a2w)
                               : 0.0f;
    float Sprev = __shfl_up(Sw, 1);
    float Sex = (lane == 0) ? 0.0f : Sprev;
    Sex = fmaf(c8lane, carry, Sex);
    float v = fmaf(cgk, vrun, Sex);
    float4 ya, yb;
    v = fmaf(c, v, scale * xa.x); ya.x = v;
    v = fmaf(c, v, scale * xa.y); ya.y = v;
    v = fmaf(c, v, scale * xa.z); ya.z = v;
    v = fmaf(c, v, scale * xa.w); ya.w = v;
    v = fmaf(c, v, scale * xb.x); yb.x = v;
    v = fmaf(c, v, scale * xb.y); yb.y = v;
    v = fmaf(c, v, scale * xb.z); yb.z = v;
    v = fmaf(c, v, scale * xb.w); yb.w = v;
    out4[(tile << 9) + 2 * t] = ya;
    out4[(tile << 9) + 2 * t + 1] = yb;
    float tS = fmaf(c512, fmaf(c512, fmaf(c512, a0, a1w), a2w), a3w);
    vrun = fmaf(c2048, vrun, tS);
  }
}

// One block per batch: preLP -> KS producer/consumer -> postLP.
// LDS map: xbuf = lds[0..8191] (4 x-segment slots, addr = n & 8191),
//          yring = lds[8192..14335] (3 y-segment slots, addr = n % 6144),
//          lws = lds[14336..14343].
__global__ void __launch_bounds__(256) synth_kernel(
    const float* __restrict__ exc, const float* __restrict__ pitch,
    const float* __restrict__ w1, const float* __restrict__ b1,
    const float* __restrict__ w2, const float* __restrict__ b2,
    const float* __restrict__ eg, float* __restrict__ buf0,
    float* __restrict__ buf1, float* __restrict__ out_scalars) {
  const int b = blockIdx.x;
  const int t = threadIdx.x;
  const int lane = t & 63;
  __shared__ float lds[14344];
  float* xbuf = lds;
  float* yring = lds + 8192;
  float* lws = lds + 14336;

  BParams P = compute_params(b, pitch, w1, b1, w2, b2);

  if (b == 0 && t == 0) {
    float slc = 0.0f, slm = 0.0f, slp = 0.0f;
    for (int i = 0; i < 8; ++i) {
      BParams Q = compute_params(i, pitch, w1, b1, w2, b2);
      slc += Q.lc;
      slm += Q.lm;
      slp += Q.lp;
    }
    out_scalars[0] = slc / 8.0f;
    out_scalars[1] = slm / 8.0f;
    out_scalars[2] = slp / 8.0f;
  }

  // phase A: pre-LP exc -> buf0
  lpc_scan2(exc + b * NSAMP, buf0 + b * NSAMP, eg[0] * P.alpha, 1.0f - P.alpha,
            t, lws);
  __syncthreads();

  const float* xg = buf0 + b * NSAMP;
  float* yg = buf1 + b * NSAMP;
  // preamble: x segs 0..2 into xbuf
  for (int i = t; i < 6144; i += 256) xbuf[i] = xg[i];

  // persistent KS state (wave 0)
  const int C = P.Di;                 // 66..735
  const int knum = (C + 63) >> 6;     // 2..12
  const float c0w = P.g * (1.0f - P.s) * (1.0f - P.fr);
  const float c1w = P.g * ((1.0f - P.s) * P.fr + P.s * (1.0f - P.fr));
  const float c2w = P.g * P.s * P.fr;
  const int kq1 = (C - 1) >> 6, lq1 = (C - 1) & 63;
  const int kq2 = (C - 2) >> 6, lq2 = (C - 2) & 63;
  int n0 = 0, rb = 0;
  float p1 = 0.0f, p2 = 0.0f;  // y[n0-C-1], y[n0-C-2]
  float yp[NK], xA[NK], xB[NK], xA2[NK], xB2[NK];
#pragma unroll
  for (int k = 0; k < NK; ++k) {
    yp[k] = 0.0f;
    xA[k] = xB[k] = xA2[k] = xB2[k] = 0.0f;
  }

  auto ks_sub = [&](float(&XC)[NK]) {
    float b2v[NK], b3v[NK];
#pragma unroll
    for (int k = 0; k < NK; ++k)
      if (k < knum) b2v[k] = shr1(yp[k], (k == 0) ? p1 : rl63(yp[k - 1]));
#pragma unroll
    for (int k = 0; k < NK; ++k)
      if (k < knum) b3v[k] = shr1(b2v[k], (k == 0) ? p2 : rl63(b2v[k - 1]));
    float p1n = p1, p2n = p2;
#pragma unroll
    for (int k = 0; k < NK; ++k) {
      if (k == kq1) p1n = rlv(yp[k], lq1);
      if (k == kq2) p2n = rlv(yp[k], lq2);
    }
#pragma unroll
    for (int k = 0; k < NK; ++k)
      if (k < knum)
        yp[k] = fmaf(c0w, yp[k], fmaf(c2w, b3v[k], fmaf(c1w, b2v[k], XC[k])));
    p1 = p1n;
    p2 = p2n;
#pragma unroll
    for (int k = 0; k < NK; ++k)
      if (k < knum) {
        int i = lane + (k << 6);
        if (i < C) {
          int ra = rb + i;
          if (ra >= 6144) ra -= 6144;
          yring[ra] = yp[k];
        }
      }
    rb += C;
    if (rb >= 6144) rb -= 6144;
    n0 += C;
  };

  for (int s = 0; s < 16; ++s) {
    __syncthreads();
    if (t < 64) {
      if (s == 0) {
#pragma unroll
        for (int k = 0; k < NK; ++k)
          if (k < knum) {
            int i = lane + (k << 6);
            xA[k] = xbuf[i & 8191];
            xB[k] = xbuf[(C + i) & 8191];
            xA2[k] = xbuf[(2 * C + i) & 8191];
            xB2[k] = xbuf[(3 * C + i) & 8191];
          }
      }
      const int fence = (s + 1) << 11;
      while (n0 < fence) {
        ks_sub(xA);
        ks_sub(xB);
#pragma unroll
        for (int k = 0; k < NK; ++k)
          if (k < knum) {
            xA[k] = xA2[k];
            xB[k] = xB2[k];
          }
#pragma unroll
        for (int k = 0; k < NK; ++k)
          if (k < knum) {
            int i = lane + (k << 6);
            xA2[k] = xbuf[(n0 + 2 * C + i) & 8191];
            xB2[k] = xbuf[(n0 + 3 * C + i) & 8191];
          }
      }
    } else {
      const int ht = t - 64;
      if (s >= 1) {
        const int sb = (s - 1) << 11;
        const int slot = ((s - 1) % 3) << 11;
        for (int i = ht; i < 2048; i += 192) yg[sb + i] = yring[slot + i];
      }
      const int ls = s + 3;
      if (ls <= 15) {
        const int xo = ls << 11;
        for (int i = ht; i < 2048; i += 192) xbuf[(xo + i) & 8191] = xg[xo + i];
      }
    }
  }
  __syncthreads();
  {
    const int sb = 15 << 11;  // seg 15 lives in ring slot 0
    for (int i = t; i < 2048; i += 256) yg[sb + i] = yring[i];
  }
  __syncthreads();

  // phase C: post-LP buf1 -> buf0
  lpc_scan2(buf1 + b * NSAMP, buf0 + b * NSAMP, P.alpha_p, 1.0f - P.alpha_p, t,
            lws);
}

// ---- body: 3 groups x 8 batches; 8 bands per block; exact affine scan ----
// pass1 computes only the offset vector (the segment matrix is the uniform
// M^128, built by repeated squaring); Kogge-Stone matrix scan; per-lane
// M^(128*lane) via binary expansion; pass2 emits sum of 8 gained bands.
__global__ void __launch_bounds__(256) body_part8(
    const float* __restrict__ xin, float* __restrict__ part,
    const float* __restrict__ gains) {
  const int grp = blockIdx.x;  // 0..2
  const int b = blockIdx.y;    // 0..7
  const int t = threadIdx.x;
  const int lane = t & 63, wid = t >> 6;

  float A1[8], A2[8], B0[8], GN[8];
#pragma unroll
  for (int j = 0; j < 8; ++j) {
    int k = grp * 8 + j;
    float fc = (float)(80.0 * pow(100.0, (double)k / 23.0));
    float w = 2.0f * PI_F * fc / FS_F;
    float r = expf(-PI_F * fc / (10.0f * FS_F));
    A1[j] = -2.0f * r * cosf(w);
    A2[j] = r * r;
    B0[j] = 1.0f - r;
    GN[j] = gains[k];
  }

  const float4* x4 = (const float4*)(xin + b * NSAMP + t * 128);
  float cv0[8], cv1[8];
#pragma unroll
  for (int j = 0; j < 8; ++j) cv0[j] = cv1[j] = 0.0f;
  for (int i = 0; i < 32; ++i) {
    float4 xv = x4[i];
#pragma unroll
    for (int e = 0; e < 4; ++e) {
      float xi = e == 0 ? xv.x : e == 1 ? xv.y : e == 2 ? xv.z : xv.w;
#pragma unroll
      for (int j = 0; j < 8; ++j) {
        float nc = fmaf(B0[j], xi, -fmaf(A1[j], cv0[j], A2[j] * cv1[j]));
        cv1[j] = cv0[j];
        cv0[j] = nc;
      }
    }
  }
  // Q = M^128 by 7 squarings of M = [[-a1,-a2],[1,0]]
  float Q00[8], Q01[8], Q10[8], Q11[8];
#pragma unroll
  for (int j = 0; j < 8; ++j) {
    Q00[j] = -A1[j]; Q01[j] = -A2[j]; Q10[j] = 1.0f; Q11[j] = 0.0f;
  }
  for (int q = 0; q < 7; ++q) {
#pragma unroll
    for (int j = 0; j < 8; ++j) {
      float n00 = fmaf(Q00[j], Q00[j], Q01[j] * Q10[j]);
      float n01 = fmaf(Q00[j], Q01[j], Q01[j] * Q11[j]);
      float n10 = fmaf(Q10[j], Q00[j], Q11[j] * Q10[j]);
      float n11 = fmaf(Q10[j], Q01[j], Q11[j] * Q11[j]);
      Q00[j] = n00; Q01[j] = n01; Q10[j] = n10; Q11[j] = n11;
    }
  }
  // snapshot T = M^128 for per-lane powers
  float T00[8], T01[8], T10[8], T11[8];
#pragma unroll
  for (int j = 0; j < 8; ++j) {
    T00[j] = Q00[j]; T01[j] = Q01[j]; T10[j] = Q10[j]; T11[j] = Q11[j];
  }
  // Kogge-Stone within wave; Q squares each step (uniform multiplier)
  for (int off = 1; off <= 32; off <<= 1) {
#pragma unroll
    for (int j = 0; j < 8; ++j) {
      float u0 = __shfl_up(cv0[j], off);
      float u1 = __shfl_up(cv1[j], off);
      if (lane >= off) {
        float nc0 = fmaf(Q00[j], u0, fmaf(Q01[j], u1, cv0[j]));
        float nc1 = fmaf(Q10[j], u0, fmaf(Q11[j], u1, cv1[j]));
        cv0[j] = nc0;
        cv1[j] = nc1;
      }
      float n00 = fmaf(Q00[j], Q00[j], Q01[j] * Q10[j]);
      float n01 = fmaf(Q00[j], Q01[j], Q01[j] * Q11[j]);
      float n10 = fmaf(Q10[j], Q00[j], Q11[j] * Q10[j]);
      float n11 = fmaf(Q10[j], Q01[j], Q11[j] * Q11[j]);
      Q00[j] = n00; Q01[j] = n01; Q10[j] = n10; Q11[j] = n11;
    }
  }
  // Q is now M^8192 (one wave span)
  __shared__ float lc0[4][8], lc1[4][8];
  if (lane == 63) {
#pragma unroll
    for (int j = 0; j < 8; ++j) {
      lc0[wid][j] = cv0[j];
      lc1[wid][j] = cv1[j];
    }
  }
  __syncthreads();
  float car0[8], car1[8];
#pragma unroll
  for (int j = 0; j < 8; ++j) car0[j] = car1[j] = 0.0f;
  for (int v = 0; v < wid; ++v) {
#pragma unroll
    for (int j = 0; j < 8; ++j) {
      float n0c = fmaf(Q00[j], car0[j], fmaf(Q01[j], car1[j], lc0[v][j]));
      float n1c = fmaf(Q10[j], car0[j], fmaf(Q11[j], car1[j], lc1[v][j]));
      car0[j] = n0c;
      car1[j] = n1c;
    }
  }
  // R = M^(128*lane), binary expansion (powers of M commute)
  float R00[8], R01[8], R10[8], R11[8];
#pragma unroll
  for (int j = 0; j < 8; ++j) {
    R00[j] = 1.0f; R01[j] = 0.0f; R10[j] = 0.0f; R11[j] = 1.0f;
  }
  for (int bit = 0; bit < 6; ++bit) {
    bool on = (lane >> bit) & 1;
#pragma unroll
    for (int j = 0; j < 8; ++j) {
      if (on) {
        float n00 = fmaf(T00[j], R00[j], T01[j] * R10[j]);
        float n01 = fmaf(T00[j], R01[j], T01[j] * R11[j]);
        float n10 = fmaf(T10[j], R00[j], T11[j] * R10[j]);
        float n11 = fmaf(T10[j], R01[j], T11[j] * R11[j]);
        R00[j] = n00; R01[j] = n01; R10[j] = n10; R11[j] = n11;
      }
      float s00 = fmaf(T00[j], T00[j], T01[j] * T10[j]);
      float s01 = fmaf(T00[j], T01[j], T01[j] * T11[j]);
      float s10 = fmaf(T10[j], T00[j], T11[j] * T10[j]);
      float s11 = fmaf(T10[j], T01[j], T11[j] * T11[j]);
      T00[j] = s00; T01[j] = s01; T10[j] = s10; T11[j] = s11;
    }
  }
  // seed state: (within-wave exclusive) + R * (cross-wave carry)
  float y1[8], y2[8];
#pragma unroll
  for (int j = 0; j < 8; ++j) {
    float e0 = __shfl_up(cv0[j], 1);
    float e1 = __shfl_up(cv1[j], 1);
    if (lane == 0) {
      e0 = 0.0f;
      e1 = 0.0f;
    }
    y1[j] = fmaf(R00[j], car0[j], fmaf(R01[j], car1[j], e0));
    y2[j] = fmaf(R10[j], car0[j], fmaf(R11[j], car1[j], e1));
  }
  // pass2: emit gained sum of 8 bands
  float4* p4 = (float4*)(part + ((size_t)(grp * 8 + b)) * NSAMP + t * 128);
  for (int i = 0; i < 32; ++i) {
    float4 xv = x4[i];
    float4 ov;
#pragma unroll
    for (int e = 0; e < 4; ++e) {
      float xi = e == 0 ? xv.x : e == 1 ? xv.y : e == 2 ? xv.z : xv.w;
      float acc = 0.0f;
#pragma unroll
      for (int j = 0; j < 8; ++j) {
        float yv = fmaf(B0[j], xi, -fmaf(A1[j], y1[j], A2[j] * y2[j]));
        y2[j] = y1[j];
        y1[j] = yv;
        acc = fmaf(GN[j], yv, acc);
      }
      if (e == 0) ov.x = acc;
      else if (e == 1) ov.y = acc;
      else if (e == 2) ov.z = acc;
      else ov.w = acc;
    }
    p4[i] = ov;
  }
}

__global__ void __launch_bounds__(256) reduce3(const float* __restrict__ part,
                                               float* __restrict__ out) {
  int idx = blockIdx.x * 256 + threadIdx.x;  // b*NSAMP + n
  out[idx] = part[idx] + part[idx + 8 * NSAMP] + part[idx + 16 * NSAMP];
}

// ---- fallback (ws too small): per-(band,batch) resonator with atomics ----
__device__ inline void body_coeffs(int k, float& a1, float& a2, float& b0) {
  float fc = (float)(80.0 * pow(100.0, (double)k / 23.0));
  float w = 2.0f * PI_F * fc / FS_F;
  float r = expf(-PI_F * fc / (10.0f * FS_F));
  a1 = -2.0f * r * cosf(w);
  a2 = r * r;
  b0 = 1.0f - r;
}

__global__ void __launch_bounds__(256) body_atomic(const float* __restrict__ xin,
                                                   float* __restrict__ out,
                                                   const float* __restrict__ gains) {
  const int k = blockIdx.x;
  const int b = blockIdx.y;
  const int t = threadIdx.x;
  const int SEG = NSAMP / 256;
  float a1, a2, b0;
  body_coeffs(k, a1, a2, b0);
  float gain = gains[k];
  const float* x = xin + b * NSAMP + t * SEG;
  float A00 = 1.0f, A01 = 0.0f, A10 = 0.0f, A11 = 1.0f, cv0 = 0.0f, cv1 = 0.0f;
  for (int i = 0; i < SEG; ++i) {
    float xi = x[i];
    float n00 = -a1 * A00 - a2 * A10;
    float n01 = -a1 * A01 - a2 * A11;
    A10 = A00; A11 = A01; A00 = n00; A01 = n01;
    float nc0 = fmaf(b0, xi, -a1 * cv0 - a2 * cv1);
    cv1 = cv0; cv0 = nc0;
  }
  __shared__ float sA0[256], sA1[256], sA2[256], sA3[256], sc0[256], sc1[256];
  __shared__ float sv0[256], sv1[256];
  sA0[t] = A00; sA1[t] = A01; sA2[t] = A10; sA3[t] = A11;
  sc0[t] = cv0; sc1[t] = cv1;
  __syncthreads();
  if (t == 0) {
    float v0 = 0.0f, v1 = 0.0f;
    for (int i = 0; i < 256; ++i) {
      sv0[i] = v0; sv1[i] = v1;
      float nv0 = sA0[i] * v0 + sA1[i] * v1 + sc0[i];
      float nv1 = sA2[i] * v0 + sA3[i] * v1 + sc1[i];
      v0 = nv0; v1 = nv1;
    }
  }
  __syncthreads();
  float y1 = sv0[t], y2 = sv1[t];
  for (int i = 0; i < SEG; ++i) {
    float yv = fmaf(b0, x[i], -a1 * y1 - a2 * y2);
    y2 = y1; y1 = yv;
    atomicAdd(&out[b * NSAMP + t * SEG + i], gain * yv);
  }
}

extern "C" void kernel_launch(void* const* d_in, const int* in_sizes, int n_in,
                              void* d_out, int out_size, void* d_ws, size_t ws_size,
                              hipStream_t stream) {
  const float* exc = (const float*)d_in[0];
  const float* pitch = (const float*)d_in[1];
  const float* w1 = (const float*)d_in[2];
  const float* b1 = (const float*)d_in[3];
  const float* w2 = (const float*)d_in[4];
  const float* b2 = (const float*)d_in[5];
  const float* eg = (const float*)d_in[6];
  const float* bg = (const float*)d_in[7];
  float* out = (float*)d_out;
  float* buf0 = (float*)d_ws;           // 8*NSAMP: exc_f, then post-LP string
  float* buf1 = buf0 + 8 * NSAMP;       // 8*NSAMP: KS output
  float* part = buf1 + 8 * NSAMP;       // 3*8*NSAMP: per-group partials

  hipLaunchKernelGGL(synth_kernel, dim3(8), dim3(256), 0, stream, exc, pitch,
                     w1, b1, w2, b2, eg, buf0, buf1, out + 8 * NSAMP);

  size_t need = (size_t)(16 + 24) * NSAMP * sizeof(float);
  if (ws_size >= need) {
    hipLaunchKernelGGL(body_part8, dim3(3, 8), dim3(256), 0, stream, buf0, part,
                       bg);
    hipLaunchKernelGGL(reduce3, dim3(8 * NSAMP / 256), dim3(256), 0, stream,
                       part, out);
  } else {
    hipMemsetAsync(d_out, 0, (size_t)(8 * NSAMP) * sizeof(float), stream);
    hipLaunchKernelGGL(body_atomic, dim3(24, 8), dim3(256), 0, stream, buf0,
                       out, bg);
  }
}

// Round 4
// 175.648 us; speedup vs baseline: 3.8298x; 3.8298x over previous
//
#include <hip/hip_runtime.h>
#include <math.h>

#define NSAMP 32768
#define FS_F 44100.0f
#define PI_F 3.14159265358979323846f

struct BParams {
  float alpha, alpha_p;
  float fr, g, s;
  int Di;
  float lc, lm, lp;
};

__device__ inline float sigmoidf_(float x) { return 1.0f / (1.0f + expf(-x)); }

__device__ inline BParams compute_params(int b, const float* __restrict__ pitch,
                                         const float* __restrict__ w1,
                                         const float* __restrict__ b1,
                                         const float* __restrict__ w2,
                                         const float* __restrict__ b2) {
  BParams P;
  float p = pitch[b];
  float h[16];
#pragma unroll
  for (int i = 0; i < 16; ++i) {
    float v = fmaf(p, w1[i], b1[i]);
    h[i] = v > 0.0f ? v : 0.0f;
  }
  float m[3];
#pragma unroll
  for (int j = 0; j < 3; ++j) {
    float acc = b2[j];
#pragma unroll
    for (int i = 0; i < 16; ++i) acc = fmaf(h[i], w2[j * 16 + i], acc);
    m[j] = acc;
  }
  P.lc = fminf(fmaxf(m[0], -2.0f), 2.5f);
  P.lm = fminf(fmaxf(m[1], -2.5f), 0.0f);
  P.lp = fminf(fmaxf(m[2], -4.0f), 4.0f);
  P.g = 0.999f * sigmoidf_(P.lc);
  P.s = sigmoidf_(P.lm);
  float f0 = fmaxf(p, 60.0f);
  float D = fminf(fmaxf(FS_F / f0, 2.0f), 735.0f);
  int Di = (int)floorf(D);
  P.fr = D - (float)Di;
  P.Di = Di;
  float mult = fminf(fmaxf(2.0f + 6.0f * (f0 - 60.0f) / 600.0f, 2.0f), 8.0f);
  float cutoff = fminf(2.0f * PI_F * f0 * mult / FS_F, PI_F * 0.9f);
  P.alpha = 1.0f - expf(-cutoff);
  float cpost = fminf(PI_F * sigmoidf_(P.lp), PI_F * 0.99f);
  P.alpha_p = 1.0f - expf(-cpost);
  return P;
}

// lane helpers (wave64)
__device__ inline float rl63(float v) {
  return __int_as_float(__builtin_amdgcn_readlane(__float_as_int(v), 63));
}
__device__ inline float rlv(float v, int l) {
  return __int_as_float(__builtin_amdgcn_readlane(__float_as_int(v), l));
}
// whole-wave shift right by 1; lane 0 takes `bnd` (uniform value)
__device__ inline float shr1(float v, float bnd) {
  return __int_as_float(__builtin_amdgcn_update_dpp(
      __float_as_int(bnd), __float_as_int(v), 0x138 /*wave_shr:1*/, 0xf, 0xf,
      false));
}

// Exact one-pole IIR y[n] = scale*x[n] + c*y[n-1] over NSAMP, 256 threads.
__device__ inline void lpc_scan2(const float* __restrict__ in,
                                 float* __restrict__ out, float scale, float c,
                                 int t, float* lws) {
  const int lane = t & 63, wid = t >> 6;
  float c2v = c * c, c4 = c2v * c2v, c8 = c4 * c4;
  float m1 = c8, m2 = m1 * m1, m4 = m2 * m2, m8 = m4 * m4, m16 = m8 * m8,
        m32 = m16 * m16;
  float c512 = m32 * m32;
  float c2048 = c512 * c512;
  c2048 *= c2048;
  float l2c = log2f(c);
  float c8lane = exp2f((float)(8 * lane) * l2c);
  float cgk = exp2f((float)(8 * t) * l2c);
  float vrun = 0.0f;
  const float4* in4 = (const float4*)in;
  float4* out4 = (float4*)out;
  for (int tile = 0; tile < 16; ++tile) {
    __syncthreads();  // lws reuse guard
    float4 xa = in4[(tile << 9) + 2 * t];
    float4 xb = in4[(tile << 9) + 2 * t + 1];
    float S = 0.0f;
    S = fmaf(c, S, scale * xa.x);
    S = fmaf(c, S, scale * xa.y);
    S = fmaf(c, S, scale * xa.z);
    S = fmaf(c, S, scale * xa.w);
    S = fmaf(c, S, scale * xb.x);
    S = fmaf(c, S, scale * xb.y);
    S = fmaf(c, S, scale * xb.z);
    S = fmaf(c, S, scale * xb.w);
    float Sw = S, u;
    u = __shfl_up(Sw, 1);
    if (lane >= 1) Sw = fmaf(m1, u, Sw);
    u = __shfl_up(Sw, 2);
    if (lane >= 2) Sw = fmaf(m2, u, Sw);
    u = __shfl_up(Sw, 4);
    if (lane >= 4) Sw = fmaf(m4, u, Sw);
    u = __shfl_up(Sw, 8);
    if (lane >= 8) Sw = fmaf(m8, u, Sw);
    u = __shfl_up(Sw, 16);
    if (lane >= 16) Sw = fmaf(m16, u, Sw);
    u = __shfl_up(Sw, 32);
    if (lane >= 32) Sw = fmaf(m32, u, Sw);
    if (lane == 63) lws[wid] = Sw;
    __syncthreads();
    float a0 = lws[0], a1w = lws[1], a2w = lws[2], a3w = lws[3];
    float carry = (wid == 1)   ? a0
                  : (wid == 2) ? fmaf(c512, a0, a1w)
                  : (wid == 3) ? fmaf(c512, fmaf(c512, a0, a1w), a2w)
                               : 0.0f;
    float Sprev = __shfl_up(Sw, 1);
    float Sex = (lane == 0) ? 0.0f : Sprev;
    Sex = fmaf(c8lane, carry, Sex);
    float v = fmaf(cgk, vrun, Sex);
    float4 ya, yb;
    v = fmaf(c, v, scale * xa.x); ya.x = v;
    v = fmaf(c, v, scale * xa.y); ya.y = v;
    v = fmaf(c, v, scale * xa.z); ya.z = v;
    v = fmaf(c, v, scale * xa.w); ya.w = v;
    v = fmaf(c, v, scale * xb.x); yb.x = v;
    v = fmaf(c, v, scale * xb.y); yb.y = v;
    v = fmaf(c, v, scale * xb.z); yb.z = v;
    v = fmaf(c, v, scale * xb.w); yb.w = v;
    out4[(tile << 9) + 2 * t] = ya;
    out4[(tile << 9) + 2 * t + 1] = yb;
    float tS = fmaf(c512, fmaf(c512, fmaf(c512, a0, a1w), a2w), a3w);
    vrun = fmaf(c2048, vrun, tS);
  }
}

// KS with compile-time slot count. Wave 0: register-resident chunk recurrence
// (chunk size C = Di; taps come from previous chunk's registers via DPP).
// Waves 1-3: stream xg->xbuf (4 segs ahead) and yring->yg (1 seg behind).
// All loop-carried values in registers; addresses maintained incrementally.
template <int KNUM>
__device__ void ks_run(const float* __restrict__ xg, float* __restrict__ yg,
                       float* xbuf, float* yring, int t, int C, float c0w,
                       float c1w, float c2w) {
  const int lane = t & 63;
  float yp[KNUM], xA[KNUM], xB[KNUM], xC[KNUM], xD[KNUM];
  int vx[KNUM], vy[KNUM];
  float p1 = 0.0f, p2 = 0.0f;  // y[n0-C-1], y[n0-C-2]
  int n0 = 0;
  const int lq1 = (C - 1) - (KNUM - 1) * 64;       // lane of y(C-1) in last slot
  const bool wr = (lane + (KNUM - 1) * 64) < C;    // last-slot store guard

  for (int s = 0; s < 16; ++s) {
    __syncthreads();
    if (t < 64) {
      if (s == 0) {
#pragma unroll
        for (int k = 0; k < KNUM; ++k) {
          int i = lane + (k << 6);
          yp[k] = 0.0f;
          xA[k] = xbuf[i];
          xB[k] = xbuf[i + C];
          xC[k] = xbuf[i + 2 * C];
          xD[k] = xbuf[i + 3 * C];
          vx[k] = (i + 4 * C) & 8191;
          vy[k] = i;
        }
      }
      const int fence = (s + 1) << 11;
      while (n0 < fence) {
        float b2v[KNUM], b3v[KNUM];
#pragma unroll
        for (int k = 0; k < KNUM; ++k)
          b2v[k] = shr1(yp[k], (k == 0) ? p1 : rl63(yp[k - 1]));
#pragma unroll
        for (int k = 0; k < KNUM; ++k)
          b3v[k] = shr1(b2v[k], (k == 0) ? p2 : rl63(b2v[k - 1]));
        float p1n = rlv(yp[KNUM - 1], lq1);   // y(C-1) of current chunk
        float p2n = rlv(b2v[KNUM - 1], lq1);  // y(C-2)
#pragma unroll
        for (int k = 0; k < KNUM; ++k) {
          float v = fmaf(c0w, yp[k], xA[k]);
          v = fmaf(c1w, b2v[k], v);
          yp[k] = fmaf(c2w, b3v[k], v);
        }
        p1 = p1n;
        p2 = p2n;
#pragma unroll
        for (int k = 0; k < KNUM; ++k) {
          if (k < KNUM - 1 || wr) yring[vy[k]] = yp[k];
          vy[k] += C;
          if (vy[k] >= 6144) vy[k] -= 6144;
        }
#pragma unroll
        for (int k = 0; k < KNUM; ++k) {
          xA[k] = xB[k];
          xB[k] = xC[k];
          xC[k] = xD[k];
          xD[k] = xbuf[vx[k]];
          vx[k] = (vx[k] + C) & 8191;
        }
        n0 += C;
      }
    } else {
      const int ht = t - 64;
      if (s >= 1) {
        const int sb = (s - 1) << 11;
        const int slot = ((s - 1) % 3) << 11;
        for (int i = ht; i < 2048; i += 192) yg[sb + i] = yring[slot + i];
      }
      const int ls = s + 3;
      if (ls <= 15) {
        const int xo = ls << 11;
        for (int i = ht; i < 2048; i += 192) xbuf[(xo + i) & 8191] = xg[xo + i];
      }
    }
  }
  __syncthreads();
  // segment 15 lives in ring slot 0 (30720 mod 6144 == 0)
  for (int i = t; i < 2048; i += 256) yg[(15 << 11) + i] = yring[i];
  __syncthreads();
}

// One block per batch: preLP -> KS -> postLP.
// LDS: xbuf[0..8191], yring[8192..14335], lws[14336..14343].
__global__ void __launch_bounds__(256) synth_kernel(
    const float* __restrict__ exc, const float* __restrict__ pitch,
    const float* __restrict__ w1, const float* __restrict__ b1,
    const float* __restrict__ w2, const float* __restrict__ b2,
    const float* __restrict__ eg, float* __restrict__ buf0,
    float* __restrict__ buf1, float* __restrict__ out_scalars) {
  const int b = blockIdx.x;
  const int t = threadIdx.x;
  __shared__ float lds[14344];
  float* xbuf = lds;
  float* yring = lds + 8192;
  float* lws = lds + 14336;

  BParams P = compute_params(b, pitch, w1, b1, w2, b2);

  if (b == 0 && t < 64) {
    // lanes 0..7 hold params of batches 0..7; readlane-sum (wave-uniform)
    int bb = (t < 8) ? t : 0;
    BParams Q = compute_params(bb, pitch, w1, b1, w2, b2);
    float slc = 0.0f, slm = 0.0f, slp = 0.0f;
    for (int i = 0; i < 8; ++i) {
      slc += rlv(Q.lc, i);
      slm += rlv(Q.lm, i);
      slp += rlv(Q.lp, i);
    }
    if (t == 0) {
      out_scalars[0] = slc / 8.0f;
      out_scalars[1] = slm / 8.0f;
      out_scalars[2] = slp / 8.0f;
    }
  }

  // phase A: pre-LP exc -> buf0
  lpc_scan2(exc + b * NSAMP, buf0 + b * NSAMP, eg[0] * P.alpha, 1.0f - P.alpha,
            t, lws);
  __syncthreads();

  const float* xg = buf0 + b * NSAMP;
  float* yg = buf1 + b * NSAMP;
  // preamble: x segments 0..2 into xbuf (ks_run's s=0 barrier publishes)
  for (int i = t; i < 6144; i += 256) xbuf[i] = xg[i];

  const int C = P.Di;  // 66..735 given pitch in [60,660]
  const float c0w = P.g * (1.0f - P.s) * (1.0f - P.fr);
  const float c1w = P.g * ((1.0f - P.s) * P.fr + P.s * (1.0f - P.fr));
  const float c2w = P.g * P.s * P.fr;
  const int knum = (C + 63) >> 6;

  switch (knum) {
    case 1:  ks_run<1>(xg, yg, xbuf, yring, t, C, c0w, c1w, c2w); break;
    case 2:  ks_run<2>(xg, yg, xbuf, yring, t, C, c0w, c1w, c2w); break;
    case 3:  ks_run<3>(xg, yg, xbuf, yring, t, C, c0w, c1w, c2w); break;
    case 4:  ks_run<4>(xg, yg, xbuf, yring, t, C, c0w, c1w, c2w); break;
    case 5:  ks_run<5>(xg, yg, xbuf, yring, t, C, c0w, c1w, c2w); break;
    case 6:  ks_run<6>(xg, yg, xbuf, yring, t, C, c0w, c1w, c2w); break;
    case 7:  ks_run<7>(xg, yg, xbuf, yring, t, C, c0w, c1w, c2w); break;
    case 8:  ks_run<8>(xg, yg, xbuf, yring, t, C, c0w, c1w, c2w); break;
    case 9:  ks_run<9>(xg, yg, xbuf, yring, t, C, c0w, c1w, c2w); break;
    case 10: ks_run<10>(xg, yg, xbuf, yring, t, C, c0w, c1w, c2w); break;
    case 11: ks_run<11>(xg, yg, xbuf, yring, t, C, c0w, c1w, c2w); break;
    default: ks_run<12>(xg, yg, xbuf, yring, t, C, c0w, c1w, c2w); break;
  }

  // phase C: post-LP buf1 -> buf0
  lpc_scan2(buf1 + b * NSAMP, buf0 + b * NSAMP, P.alpha_p, 1.0f - P.alpha_p, t,
            lws);
}

// ---- body: 3 groups x 8 batches; 8 bands per block; exact affine scan ----
__global__ void __launch_bounds__(256) body_part8(
    const float* __restrict__ xin, float* __restrict__ part,
    const float* __restrict__ gains) {
  const int grp = blockIdx.x;  // 0..2
  const int b = blockIdx.y;    // 0..7
  const int t = threadIdx.x;
  const int lane = t & 63, wid = t >> 6;

  float A1[8], A2[8], B0[8], GN[8];
#pragma unroll
  for (int j = 0; j < 8; ++j) {
    int k = grp * 8 + j;
    // fc = 80 * 100^(k/23) = 80 * exp2(k * log2(100)/23)
    float fc = 80.0f * exp2f((float)k * (6.64385618977472436f / 23.0f));
    float w = 2.0f * PI_F * fc / FS_F;
    float r = expf(-PI_F * fc / (10.0f * FS_F));
    A1[j] = -2.0f * r * cosf(w);
    A2[j] = r * r;
    B0[j] = 1.0f - r;
    GN[j] = gains[k];
  }

  const float4* x4 = (const float4*)(xin + b * NSAMP + t * 128);
  float cv0[8], cv1[8];
#pragma unroll
  for (int j = 0; j < 8; ++j) cv0[j] = cv1[j] = 0.0f;
  for (int i = 0; i < 32; ++i) {
    float4 xv = x4[i];
#pragma unroll
    for (int e = 0; e < 4; ++e) {
      float xi = e == 0 ? xv.x : e == 1 ? xv.y : e == 2 ? xv.z : xv.w;
#pragma unroll
      for (int j = 0; j < 8; ++j) {
        float nc = fmaf(B0[j], xi, -fmaf(A1[j], cv0[j], A2[j] * cv1[j]));
        cv1[j] = cv0[j];
        cv0[j] = nc;
      }
    }
  }
  float Q00[8], Q01[8], Q10[8], Q11[8];
#pragma unroll
  for (int j = 0; j < 8; ++j) {
    Q00[j] = -A1[j]; Q01[j] = -A2[j]; Q10[j] = 1.0f; Q11[j] = 0.0f;
  }
  for (int q = 0; q < 7; ++q) {
#pragma unroll
    for (int j = 0; j < 8; ++j) {
      float n00 = fmaf(Q00[j], Q00[j], Q01[j] * Q10[j]);
      float n01 = fmaf(Q00[j], Q01[j], Q01[j] * Q11[j]);
      float n10 = fmaf(Q10[j], Q00[j], Q11[j] * Q10[j]);
      float n11 = fmaf(Q10[j], Q01[j], Q11[j] * Q11[j]);
      Q00[j] = n00; Q01[j] = n01; Q10[j] = n10; Q11[j] = n11;
    }
  }
  float T00[8], T01[8], T10[8], T11[8];
#pragma unroll
  for (int j = 0; j < 8; ++j) {
    T00[j] = Q00[j]; T01[j] = Q01[j]; T10[j] = Q10[j]; T11[j] = Q11[j];
  }
  for (int off = 1; off <= 32; off <<= 1) {
#pragma unroll
    for (int j = 0; j < 8; ++j) {
      float u0 = __shfl_up(cv0[j], off);
      float u1 = __shfl_up(cv1[j], off);
      if (lane >= off) {
        float nc0 = fmaf(Q00[j], u0, fmaf(Q01[j], u1, cv0[j]));
        float nc1 = fmaf(Q10[j], u0, fmaf(Q11[j], u1, cv1[j]));
        cv0[j] = nc0;
        cv1[j] = nc1;
      }
      float n00 = fmaf(Q00[j], Q00[j], Q01[j] * Q10[j]);
      float n01 = fmaf(Q00[j], Q01[j], Q01[j] * Q11[j]);
      float n10 = fmaf(Q10[j], Q00[j], Q11[j] * Q10[j]);
      float n11 = fmaf(Q10[j], Q01[j], Q11[j] * Q11[j]);
      Q00[j] = n00; Q01[j] = n01; Q10[j] = n10; Q11[j] = n11;
    }
  }
  __shared__ float lc0[4][8], lc1[4][8];
  if (lane == 63) {
#pragma unroll
    for (int j = 0; j < 8; ++j) {
      lc0[wid][j] = cv0[j];
      lc1[wid][j] = cv1[j];
    }
  }
  __syncthreads();
  float car0[8], car1[8];
#pragma unroll
  for (int j = 0; j < 8; ++j) car0[j] = car1[j] = 0.0f;
  for (int v = 0; v < wid; ++v) {
#pragma unroll
    for (int j = 0; j < 8; ++j) {
      float n0c = fmaf(Q00[j], car0[j], fmaf(Q01[j], car1[j], lc0[v][j]));
      float n1c = fmaf(Q10[j], car0[j], fmaf(Q11[j], car1[j], lc1[v][j]));
      car0[j] = n0c;
      car1[j] = n1c;
    }
  }
  float R00[8], R01[8], R10[8], R11[8];
#pragma unroll
  for (int j = 0; j < 8; ++j) {
    R00[j] = 1.0f; R01[j] = 0.0f; R10[j] = 0.0f; R11[j] = 1.0f;
  }
  for (int bit = 0; bit < 6; ++bit) {
    bool on = (lane >> bit) & 1;
#pragma unroll
    for (int j = 0; j < 8; ++j) {
      if (on) {
        float n00 = fmaf(T00[j], R00[j], T01[j] * R10[j]);
        float n01 = fmaf(T00[j], R01[j], T01[j] * R11[j]);
        float n10 = fmaf(T10[j], R00[j], T11[j] * R10[j]);
        float n11 = fmaf(T10[j], R01[j], T11[j] * R11[j]);
        R00[j] = n00; R01[j] = n01; R10[j] = n10; R11[j] = n11;
      }
      float s00 = fmaf(T00[j], T00[j], T01[j] * T10[j]);
      float s01 = fmaf(T00[j], T01[j], T01[j] * T11[j]);
      float s10 = fmaf(T10[j], T00[j], T11[j] * T10[j]);
      float s11 = fmaf(T10[j], T01[j], T11[j] * T11[j]);
      T00[j] = s00; T01[j] = s01; T10[j] = s10; T11[j] = s11;
    }
  }
  float y1[8], y2[8];
#pragma unroll
  for (int j = 0; j < 8; ++j) {
    float e0 = __shfl_up(cv0[j], 1);
    float e1 = __shfl_up(cv1[j], 1);
    if (lane == 0) {
      e0 = 0.0f;
      e1 = 0.0f;
    }
    y1[j] = fmaf(R00[j], car0[j], fmaf(R01[j], car1[j], e0));
    y2[j] = fmaf(R10[j], car0[j], fmaf(R11[j], car1[j], e1));
  }
  float4* p4 = (float4*)(part + ((size_t)(grp * 8 + b)) * NSAMP + t * 128);
  for (int i = 0; i < 32; ++i) {
    float4 xv = x4[i];
    float4 ov;
#pragma unroll
    for (int e = 0; e < 4; ++e) {
      float xi = e == 0 ? xv.x : e == 1 ? xv.y : e == 2 ? xv.z : xv.w;
      float acc = 0.0f;
#pragma unroll
      for (int j = 0; j < 8; ++j) {
        float yv = fmaf(B0[j], xi, -fmaf(A1[j], y1[j], A2[j] * y2[j]));
        y2[j] = y1[j];
        y1[j] = yv;
        acc = fmaf(GN[j], yv, acc);
      }
      if (e == 0) ov.x = acc;
      else if (e == 1) ov.y = acc;
      else if (e == 2) ov.z = acc;
      else ov.w = acc;
    }
    p4[i] = ov;
  }
}

__global__ void __launch_bounds__(256) reduce3(const float* __restrict__ part,
                                               float* __restrict__ out) {
  int idx = blockIdx.x * 256 + threadIdx.x;
  out[idx] = part[idx] + part[idx + 8 * NSAMP] + part[idx + 16 * NSAMP];
}

// ---- fallback (ws too small): per-(band,batch) resonator with atomics ----
__global__ void __launch_bounds__(256) body_atomic(const float* __restrict__ xin,
                                                   float* __restrict__ out,
                                                   const float* __restrict__ gains) {
  const int k = blockIdx.x;
  const int b = blockIdx.y;
  const int t = threadIdx.x;
  const int SEG = NSAMP / 256;
  float fc = 80.0f * exp2f((float)k * (6.64385618977472436f / 23.0f));
  float w = 2.0f * PI_F * fc / FS_F;
  float r = expf(-PI_F * fc / (10.0f * FS_F));
  float a1 = -2.0f * r * cosf(w);
  float a2 = r * r;
  float b0 = 1.0f - r;
  float gain = gains[k];
  const float* x = xin + b * NSAMP + t * SEG;
  float A00 = 1.0f, A01 = 0.0f, A10 = 0.0f, A11 = 1.0f, cv0 = 0.0f, cv1 = 0.0f;
  for (int i = 0; i < SEG; ++i) {
    float xi = x[i];
    float n00 = -a1 * A00 - a2 * A10;
    float n01 = -a1 * A01 - a2 * A11;
    A10 = A00; A11 = A01; A00 = n00; A01 = n01;
    float nc0 = fmaf(b0, xi, -a1 * cv0 - a2 * cv1);
    cv1 = cv0; cv0 = nc0;
  }
  __shared__ float sA0[256], sA1[256], sA2[256], sA3[256], sc0[256], sc1[256];
  __shared__ float sv0[256], sv1[256];
  sA0[t] = A00; sA1[t] = A01; sA2[t] = A10; sA3[t] = A11;
  sc0[t] = cv0; sc1[t] = cv1;
  __syncthreads();
  if (t == 0) {
    float v0 = 0.0f, v1 = 0.0f;
    for (int i = 0; i < 256; ++i) {
      sv0[i] = v0; sv1[i] = v1;
      float nv0 = sA0[i] * v0 + sA1[i] * v1 + sc0[i];
      float nv1 = sA2[i] * v0 + sA3[i] * v1 + sc1[i];
      v0 = nv0; v1 = nv1;
    }
  }
  __syncthreads();
  float y1 = sv0[t], y2 = sv1[t];
  for (int i = 0; i < SEG; ++i) {
    float yv = fmaf(b0, x[i], -a1 * y1 - a2 * y2);
    y2 = y1; y1 = yv;
    atomicAdd(&out[b * NSAMP + t * SEG + i], gain * yv);
  }
}

extern "C" void kernel_launch(void* const* d_in, const int* in_sizes, int n_in,
                              void* d_out, int out_size, void* d_ws, size_t ws_size,
                              hipStream_t stream) {
  const float* exc = (const float*)d_in[0];
  const float* pitch = (const float*)d_in[1];
  const float* w1 = (const float*)d_in[2];
  const float* b1 = (const float*)d_in[3];
  const float* w2 = (const float*)d_in[4];
  const float* b2 = (const float*)d_in[5];
  const float* eg = (const float*)d_in[6];
  const float* bg = (const float*)d_in[7];
  float* out = (float*)d_out;
  float* buf0 = (float*)d_ws;           // 8*NSAMP: exc_f, then post-LP string
  float* buf1 = buf0 + 8 * NSAMP;       // 8*NSAMP: KS output
  float* part = buf1 + 8 * NSAMP;       // 3*8*NSAMP: per-group partials

  hipLaunchKernelGGL(synth_kernel, dim3(8), dim3(256), 0, stream, exc, pitch,
                     w1, b1, w2, b2, eg, buf0, buf1, out + 8 * NSAMP);

  size_t need = (size_t)(16 + 24) * NSAMP * sizeof(float);
  if (ws_size >= need) {
    hipLaunchKernelGGL(body_part8, dim3(3, 8), dim3(256), 0, stream, buf0, part,
                       bg);
    hipLaunchKernelGGL(reduce3, dim3(8 * NSAMP / 256), dim3(256), 0, stream,
                       part, out);
  } else {
    hipMemsetAsync(d_out, 0, (size_t)(8 * NSAMP) * sizeof(float), stream);
    hipLaunchKernelGGL(body_atomic, dim3(24, 8), dim3(256), 0, stream, buf0,
                       out, bg);
  }
}